// Round 6
// baseline (1912.953 us; speedup 1.0000x reference)
//
#include <hip/hip_runtime.h>
#include <math.h>

#define EPS 1e-12f

// ---------------------------------------------------------------------------
// Kernel A: L2-normalize key rows (4096 x 64) into workspace.
// ---------------------------------------------------------------------------
__global__ __launch_bounds__(256)
void nkeys_kernel(const float* __restrict__ keys, float* __restrict__ kn)
{
    const int m = blockIdx.x * 256 + threadIdx.x;   // 0..4095
    const float4* src = reinterpret_cast<const float4*>(keys + (size_t)m * 64);
    float4 v[16];
    float s0 = 0.f, s1 = 0.f, s2 = 0.f, s3 = 0.f;
#pragma unroll
    for (int i = 0; i < 16; ++i) {
        v[i] = src[i];
        s0 = fmaf(v[i].x, v[i].x, s0);
        s1 = fmaf(v[i].y, v[i].y, s1);
        s2 = fmaf(v[i].z, v[i].z, s2);
        s3 = fmaf(v[i].w, v[i].w, s3);
    }
    const float n = sqrtf((s0 + s1) + (s2 + s3));
    const float d = fmaxf(n, EPS);
    float4* dst = reinterpret_cast<float4*>(kn + (size_t)m * 64);
#pragma unroll
    for (int i = 0; i < 16; ++i) {
        float4 o;
        o.x = v[i].x / d; o.y = v[i].y / d; o.z = v[i].z / d; o.w = v[i].w / d;
        dst[i] = o;
    }
}

// ---------------------------------------------------------------------------
// Kernel B: block = 4 waves, all owning the SAME 64 query rows (lane = row).
// Wave w scans key slice [w*1024, (w+1)*1024) -> per-lane top-8 (packed u64,
// tie-correct) -> LDS merge of 4x8 -> softmax -> channel-split value gather.
// Split-K across waves gives >=4 co-resident waves/SIMD-group for latency
// overlap at unchanged total FMA work.
// ---------------------------------------------------------------------------
__global__ __launch_bounds__(256)
void kvmem_kernel(const float* __restrict__ q,       // [16][64][4096]
                  const float* __restrict__ kn,      // [4096][64] normalized
                  const float* __restrict__ values,  // [4096][64] raw
                  float* __restrict__ out)           // [16][64][4096]
{
    const int lane = threadIdx.x & 63;
    const int w    = threadIdx.x >> 6;               // wave in block: 0..3
    const int row  = (blockIdx.x << 6) + lane;       // global query row
    const int b    = row >> 12;                      // batch
    const int hw   = row & 4095;                     // spatial index

    __shared__ unsigned long long cand[4][64][9];    // padded: 18 KB

    // ---- load own q row (coalesced per-c: lanes are adjacent hw) ----
    const float* qb = q + (size_t)b * 262144 + hw;
    float qreg[64];
#pragma unroll
    for (int c = 0; c < 64; ++c) qreg[c] = qb[(size_t)c * 4096];

    // ---- normalize (matches ref eps; IEEE div) ----
    {
        float s0 = 0.f, s1 = 0.f, s2 = 0.f, s3 = 0.f;
#pragma unroll
        for (int c = 0; c < 64; c += 4) {
            s0 = fmaf(qreg[c + 0], qreg[c + 0], s0);
            s1 = fmaf(qreg[c + 1], qreg[c + 1], s1);
            s2 = fmaf(qreg[c + 2], qreg[c + 2], s2);
            s3 = fmaf(qreg[c + 3], qreg[c + 3], s3);
        }
        const float d = fmaxf(sqrtf((s0 + s1) + (s2 + s3)), EPS);
#pragma unroll
        for (int c = 0; c < 64; ++c) qreg[c] = qreg[c] / d;
    }

    // ---- per-wave top-8 over its 1024-key slice ----
    // packed u64 = sortable(sim)<<12 | (4095 - idx): desc order == (sim desc,
    // idx asc) -> exactly jax.lax.top_k's tie rule, globally consistent
    // across waves so the LDS merge stays tie-correct.
    unsigned long long pks[8];
#pragma unroll
    for (int j = 0; j < 8; ++j) pks[j] = 0x7FFFFFull << 12;   // ~ -inf
    float thr = -INFINITY;

    const float4* kn4  = reinterpret_cast<const float4*>(kn);
    const float4* base = kn4 + (size_t)(w * 1024) * 16;

    float4 ka[8], kb[8];
#pragma unroll
    for (int i = 0; i < 8; ++i) ka[i] = base[i];              // slice key 0, lo

    for (int m = 0; m < 1024; ++m) {
        const float4* kc = base + (size_t)m * 16;
#pragma unroll
        for (int i = 0; i < 8; ++i) kb[i] = kc[8 + i];        // hi half of m

        float a0 = 0.f, a1 = 0.f, a2 = 0.f, a3 = 0.f;
#pragma unroll
        for (int i = 0; i < 8; ++i) {
            a0 = fmaf(qreg[4 * i + 0], ka[i].x, a0);
            a1 = fmaf(qreg[4 * i + 1], ka[i].y, a1);
            a2 = fmaf(qreg[4 * i + 2], ka[i].z, a2);
            a3 = fmaf(qreg[4 * i + 3], ka[i].w, a3);
        }
        // prefetch lo half of key m+1 (clamped on last iter)
        const float4* kp = base + (size_t)(m < 1023 ? m + 1 : 1023) * 16;
#pragma unroll
        for (int i = 0; i < 8; ++i) ka[i] = kp[i];
#pragma unroll
        for (int i = 0; i < 8; ++i) {
            a0 = fmaf(qreg[32 + 4 * i + 0], kb[i].x, a0);
            a1 = fmaf(qreg[32 + 4 * i + 1], kb[i].y, a1);
            a2 = fmaf(qreg[32 + 4 * i + 2], kb[i].z, a2);
            a3 = fmaf(qreg[32 + 4 * i + 3], kb[i].w, a3);
        }
        const float sim = (a0 + a1) + (a2 + a3);

        if (sim > thr) {                                      // rare per wave
            unsigned int su = __float_as_uint(sim);
            su ^= (unsigned int)((int)su >> 31) | 0x80000000u;
            const int gidx = (w << 10) + m;
            unsigned long long cv =
                ((unsigned long long)su << 12) |
                (unsigned long long)(4095 - gidx);
#pragma unroll
            for (int j = 0; j < 8; ++j) {                     // bubble insert
                const unsigned long long o = pks[j];
                const bool sw = cv > o;
                pks[j] = sw ? cv : o;
                cv     = sw ? o  : cv;
            }
            const unsigned int u7 = (unsigned int)(pks[7] >> 12);
            const unsigned int s7 =
                (u7 & 0x80000000u) ? (u7 ^ 0x80000000u) : ~u7;
            thr = __uint_as_float(s7);
        }
    }

    // ---- publish per-wave lists, merge 32 -> 8 (redundant per wave) ----
#pragma unroll
    for (int j = 0; j < 8; ++j) cand[w][lane][j] = pks[j];
    __syncthreads();

    unsigned long long res[8];
#pragma unroll
    for (int j = 0; j < 8; ++j) res[j] = 0x7FFFFFull << 12;
#pragma unroll
    for (int w2 = 0; w2 < 4; ++w2) {
#pragma unroll
        for (int j = 0; j < 8; ++j) {
            unsigned long long cv = cand[w2][lane][j];
            if (cv > res[7]) {
#pragma unroll
                for (int k = 0; k < 8; ++k) {
                    const unsigned long long o = res[k];
                    const bool sw = cv > o;
                    res[k] = sw ? cv : o;
                    cv     = sw ? o  : cv;
                }
            }
        }
    }

    // ---- unpack exact top-8 sims + indices ----
    float wv[8];
    int   id[8];
#pragma unroll
    for (int j = 0; j < 8; ++j) {
        const unsigned int u  = (unsigned int)(res[j] >> 12);
        const unsigned int su = (u & 0x80000000u) ? (u ^ 0x80000000u) : ~u;
        wv[j] = __uint_as_float(su);
        id[j] = 4095 - (int)((unsigned int)res[j] & 0xFFFu);
    }

    // ---- softmax over 8 (wv[0] is max: sorted desc) ----
    const float mx = wv[0];
    float e[8];
    float esum = 0.f;
#pragma unroll
    for (int j = 0; j < 8; ++j) { e[j] = expf(wv[j] - mx); esum += e[j]; }
#pragma unroll
    for (int j = 0; j < 8; ++j) e[j] = e[j] / esum;

    // ---- channel-split epilogue: wave w owns channels [16w, 16w+16) ----
    float acc[16];
#pragma unroll
    for (int i = 0; i < 16; ++i) acc[i] = 0.f;
#pragma unroll
    for (int j = 0; j < 8; ++j) {
        const float4* vr = reinterpret_cast<const float4*>(
            values + (size_t)id[j] * 64 + (w << 4));
        const float wj = e[j];
#pragma unroll
        for (int i = 0; i < 4; ++i) {
            const float4 v = vr[i];
            acc[4 * i + 0] = fmaf(wj, v.x, acc[4 * i + 0]);
            acc[4 * i + 1] = fmaf(wj, v.y, acc[4 * i + 1]);
            acc[4 * i + 2] = fmaf(wj, v.z, acc[4 * i + 2]);
            acc[4 * i + 3] = fmaf(wj, v.w, acc[4 * i + 3]);
        }
    }

    // ---- coalesced store: per c, lanes write adjacent hw ----
    float* ob = out + (size_t)b * 262144 + hw;
#pragma unroll
    for (int i = 0; i < 16; ++i)
        ob[(size_t)((w << 4) + i) * 4096] = acc[i];
}

// ---------------------------------------------------------------------------
extern "C" void kernel_launch(void* const* d_in, const int* in_sizes, int n_in,
                              void* d_out, int out_size, void* d_ws, size_t ws_size,
                              hipStream_t stream)
{
    const float* q      = (const float*)d_in[0];   // [16][64][64][64]
    const float* keys   = (const float*)d_in[1];   // [4096][64]
    const float* values = (const float*)d_in[2];   // [4096][64]
    float*       out    = (float*)d_out;           // [16][64][64][64]
    float*       kn     = (float*)d_ws;            // 4096*64 floats = 1 MB

    nkeys_kernel<<<16, 256, 0, stream>>>(keys, kn);
    kvmem_kernel<<<1024, 256, 0, stream>>>(q, kn, values, out);
}

// Round 9
// 1909.241 us; speedup vs baseline: 1.0019x; 1.0019x over previous
//
#include <hip/hip_runtime.h>
#include <math.h>

#define EPS 1e-12f

// ---------------------------------------------------------------------------
// Kernel A: L2-normalize key rows (4096 x 64) into workspace.
// ---------------------------------------------------------------------------
__global__ __launch_bounds__(256)
void nkeys_kernel(const float* __restrict__ keys, float* __restrict__ kn)
{
    const int m = blockIdx.x * 256 + threadIdx.x;   // 0..4095
    const float4* src = reinterpret_cast<const float4*>(keys + (size_t)m * 64);
    float4 v[16];
    float s0 = 0.f, s1 = 0.f, s2 = 0.f, s3 = 0.f;
#pragma unroll
    for (int i = 0; i < 16; ++i) {
        v[i] = src[i];
        s0 = fmaf(v[i].x, v[i].x, s0);
        s1 = fmaf(v[i].y, v[i].y, s1);
        s2 = fmaf(v[i].z, v[i].z, s2);
        s3 = fmaf(v[i].w, v[i].w, s3);
    }
    const float n = sqrtf((s0 + s1) + (s2 + s3));
    const float d = fmaxf(n, EPS);
    float4* dst = reinterpret_cast<float4*>(kn + (size_t)m * 64);
#pragma unroll
    for (int i = 0; i < 16; ++i) {
        float4 o;
        o.x = v[i].x / d; o.y = v[i].y / d; o.z = v[i].z / d; o.w = v[i].w / d;
        dst[i] = o;
    }
}

// ---------------------------------------------------------------------------
// Kernel B: block = 4 waves, all owning the SAME 64 query rows (lane = row).
// Wave w scans key slice [w*1024, (w+1)*1024) -> per-lane top-8 (packed u64,
// tie-correct) -> LDS merge of 4x8 -> softmax -> channel-split value gather.
//
// __launch_bounds__(256, 2): min 2 waves/EU -> VGPR cap 256. The working set
// (qreg 64 + key dbuf 64 + pks 16 + addr ~10 ~= 155 VGPR) must stay in
// registers; without this hint the allocator capped at 80 VGPR and spilled
// qreg to scratch (measured: 2022us, VALUBusy 50%). At ~155 VGPR we get
// 3 waves/SIMD, which the 4-wave split-K structure uses for latency hiding.
// ---------------------------------------------------------------------------
__global__ __launch_bounds__(256, 2)
void kvmem_kernel(const float* __restrict__ q,       // [16][64][4096]
                  const float* __restrict__ kn,      // [4096][64] normalized
                  const float* __restrict__ values,  // [4096][64] raw
                  float* __restrict__ out)           // [16][64][4096]
{
    const int lane = threadIdx.x & 63;
    const int w    = threadIdx.x >> 6;               // wave in block: 0..3
    const int row  = (blockIdx.x << 6) + lane;       // global query row
    const int b    = row >> 12;                      // batch
    const int hw   = row & 4095;                     // spatial index

    __shared__ unsigned long long cand[4][64][9];    // padded: 18 KB

    // ---- load own q row (coalesced per-c: lanes are adjacent hw) ----
    const float* qb = q + (size_t)b * 262144 + hw;
    float qreg[64];
#pragma unroll
    for (int c = 0; c < 64; ++c) qreg[c] = qb[(size_t)c * 4096];

    // ---- normalize (matches ref eps; IEEE div) ----
    {
        float s0 = 0.f, s1 = 0.f, s2 = 0.f, s3 = 0.f;
#pragma unroll
        for (int c = 0; c < 64; c += 4) {
            s0 = fmaf(qreg[c + 0], qreg[c + 0], s0);
            s1 = fmaf(qreg[c + 1], qreg[c + 1], s1);
            s2 = fmaf(qreg[c + 2], qreg[c + 2], s2);
            s3 = fmaf(qreg[c + 3], qreg[c + 3], s3);
        }
        const float d = fmaxf(sqrtf((s0 + s1) + (s2 + s3)), EPS);
#pragma unroll
        for (int c = 0; c < 64; ++c) qreg[c] = qreg[c] / d;
    }

    // ---- per-wave top-8 over its 1024-key slice ----
    // packed u64 = sortable(sim)<<12 | (4095 - idx): desc order == (sim desc,
    // idx asc) -> exactly jax.lax.top_k's tie rule, globally consistent
    // across waves so the LDS merge stays tie-correct.
    unsigned long long pks[8];
#pragma unroll
    for (int j = 0; j < 8; ++j) pks[j] = 0x7FFFFFull << 12;   // ~ -inf
    float thr = -INFINITY;

    const float4* kn4  = reinterpret_cast<const float4*>(kn);
    const float4* base = kn4 + (size_t)(w * 1024) * 16;

    float4 ka[8], kb[8];
#pragma unroll
    for (int i = 0; i < 8; ++i) ka[i] = base[i];              // slice key 0, lo

    for (int m = 0; m < 1024; ++m) {
        const float4* kc = base + (size_t)m * 16;
#pragma unroll
        for (int i = 0; i < 8; ++i) kb[i] = kc[8 + i];        // hi half of m

        float a0 = 0.f, a1 = 0.f, a2 = 0.f, a3 = 0.f;
#pragma unroll
        for (int i = 0; i < 8; ++i) {
            a0 = fmaf(qreg[4 * i + 0], ka[i].x, a0);
            a1 = fmaf(qreg[4 * i + 1], ka[i].y, a1);
            a2 = fmaf(qreg[4 * i + 2], ka[i].z, a2);
            a3 = fmaf(qreg[4 * i + 3], ka[i].w, a3);
        }
        // prefetch lo half of key m+1 (clamped on last iter)
        const float4* kp = base + (size_t)(m < 1023 ? m + 1 : 1023) * 16;
#pragma unroll
        for (int i = 0; i < 8; ++i) ka[i] = kp[i];
#pragma unroll
        for (int i = 0; i < 8; ++i) {
            a0 = fmaf(qreg[32 + 4 * i + 0], kb[i].x, a0);
            a1 = fmaf(qreg[32 + 4 * i + 1], kb[i].y, a1);
            a2 = fmaf(qreg[32 + 4 * i + 2], kb[i].z, a2);
            a3 = fmaf(qreg[32 + 4 * i + 3], kb[i].w, a3);
        }
        const float sim = (a0 + a1) + (a2 + a3);

        if (sim > thr) {                                      // rare per wave
            unsigned int su = __float_as_uint(sim);
            su ^= (unsigned int)((int)su >> 31) | 0x80000000u;
            const int gidx = (w << 10) + m;
            unsigned long long cv =
                ((unsigned long long)su << 12) |
                (unsigned long long)(4095 - gidx);
#pragma unroll
            for (int j = 0; j < 8; ++j) {                     // bubble insert
                const unsigned long long o = pks[j];
                const bool sw = cv > o;
                pks[j] = sw ? cv : o;
                cv     = sw ? o  : cv;
            }
            const unsigned int u7 = (unsigned int)(pks[7] >> 12);
            const unsigned int s7 =
                (u7 & 0x80000000u) ? (u7 ^ 0x80000000u) : ~u7;
            thr = __uint_as_float(s7);
        }
    }

    // ---- publish per-wave lists, merge 32 -> 8 (redundant per wave) ----
#pragma unroll
    for (int j = 0; j < 8; ++j) cand[w][lane][j] = pks[j];
    __syncthreads();

    unsigned long long res[8];
#pragma unroll
    for (int j = 0; j < 8; ++j) res[j] = 0x7FFFFFull << 12;
#pragma unroll
    for (int w2 = 0; w2 < 4; ++w2) {
#pragma unroll
        for (int j = 0; j < 8; ++j) {
            unsigned long long cv = cand[w2][lane][j];
            if (cv > res[7]) {
#pragma unroll
                for (int k = 0; k < 8; ++k) {
                    const unsigned long long o = res[k];
                    const bool sw = cv > o;
                    res[k] = sw ? cv : o;
                    cv     = sw ? o  : cv;
                }
            }
        }
    }

    // ---- unpack exact top-8 sims + indices ----
    float wv[8];
    int   id[8];
#pragma unroll
    for (int j = 0; j < 8; ++j) {
        const unsigned int u  = (unsigned int)(res[j] >> 12);
        const unsigned int su = (u & 0x80000000u) ? (u ^ 0x80000000u) : ~u;
        wv[j] = __uint_as_float(su);
        id[j] = 4095 - (int)((unsigned int)res[j] & 0xFFFu);
    }

    // ---- softmax over 8 (wv[0] is max: sorted desc) ----
    const float mx = wv[0];
    float e[8];
    float esum = 0.f;
#pragma unroll
    for (int j = 0; j < 8; ++j) { e[j] = expf(wv[j] - mx); esum += e[j]; }
#pragma unroll
    for (int j = 0; j < 8; ++j) e[j] = e[j] / esum;

    // ---- channel-split epilogue: wave w owns channels [16w, 16w+16) ----
    float acc[16];
#pragma unroll
    for (int i = 0; i < 16; ++i) acc[i] = 0.f;
#pragma unroll
    for (int j = 0; j < 8; ++j) {
        const float4* vr = reinterpret_cast<const float4*>(
            values + (size_t)id[j] * 64 + (w << 4));
        const float wj = e[j];
#pragma unroll
        for (int i = 0; i < 4; ++i) {
            const float4 v = vr[i];
            acc[4 * i + 0] = fmaf(wj, v.x, acc[4 * i + 0]);
            acc[4 * i + 1] = fmaf(wj, v.y, acc[4 * i + 1]);
            acc[4 * i + 2] = fmaf(wj, v.z, acc[4 * i + 2]);
            acc[4 * i + 3] = fmaf(wj, v.w, acc[4 * i + 3]);
        }
    }

    // ---- coalesced store: per c, lanes write adjacent hw ----
    float* ob = out + (size_t)b * 262144 + hw;
#pragma unroll
    for (int i = 0; i < 16; ++i)
        ob[(size_t)((w << 4) + i) * 4096] = acc[i];
}

// ---------------------------------------------------------------------------
extern "C" void kernel_launch(void* const* d_in, const int* in_sizes, int n_in,
                              void* d_out, int out_size, void* d_ws, size_t ws_size,
                              hipStream_t stream)
{
    const float* q      = (const float*)d_in[0];   // [16][64][64][64]
    const float* keys   = (const float*)d_in[1];   // [4096][64]
    const float* values = (const float*)d_in[2];   // [4096][64]
    float*       out    = (float*)d_out;           // [16][64][64][64]
    float*       kn     = (float*)d_ws;            // 4096*64 floats = 1 MB

    nkeys_kernel<<<16, 256, 0, stream>>>(keys, kn);
    kvmem_kernel<<<1024, 256, 0, stream>>>(q, kn, values, out);
}